// Round 12
// baseline (196.524 us; speedup 1.0000x reference)
//
#include <hip/hip_runtime.h>
#include <hip/hip_fp16.h>
#include <stdint.h>

typedef float f4 __attribute__((ext_vector_type(4)));
typedef float f32x4 __attribute__((ext_vector_type(4)));
typedef _Float16 f16x8 __attribute__((ext_vector_type(8)));

#define BSHIFT 8
#define BMASK  255
#define BCAP   8192   // edges per 256-node bucket (mean 4096 -> huge headroom)

// g-tables are SEGMENT-MAJOR: 4 sub-tables of 64 B/row.
//   element (row r, col c) lives at  sub(c>>5) + r*32 + (c&31)   [halfs]
//   sub(p) = base + p * nrows * 32
// Pass p of aggregation touches only sub(p): 3.2 MB < 4 MB per-XCD L2.

// ---------- prep: zero gcur + transpose W1/W2 -> fp16 [c][k] (replaces memset) ----------
__global__ __launch_bounds__(256) void prep_kernel(const float* __restrict__ W1,
                                                   const float* __restrict__ W2,
                                                   __half* __restrict__ Wt1,
                                                   __half* __restrict__ Wt2,
                                                   int* __restrict__ gcur) {
    int t = threadIdx.x, b = blockIdx.x;
    if (b == 0) { gcur[t] = 0; return; }
    int wi = (b - 1) >> 3, bi = (b - 1) & 7;
    const f4* w4 = (const f4*)(wi ? W2 : W1);
    _Float16* dst = (_Float16*)(wi ? Wt2 : Wt1);
#pragma unroll
    for (int it = 0; it < 2; ++it) {
        int chunk = bi * 512 + it * 256 + t;      // f4 index into 128x128 W
        f4 v = w4[chunk];
        int k = chunk >> 5, c0 = (chunk << 2) & 127;
#pragma unroll
        for (int u = 0; u < 4; ++u)
            dst[(size_t)(c0 + u) * 128 + k] = (_Float16)v[u];
    }
}

// ---------- stage B (Wt fp16 [c][k]) into swizzled LDS: byte^=((c&7)<<4) ----------
__device__ __forceinline__ void stage_B(_Float16* Bsw, const __half* __restrict__ Wt) {
    int t = threadIdx.x;
    const f4* wsrc = (const f4*)Wt;
#pragma unroll
    for (int i = 0; i < 8; ++i) {
        int cb = i * 256 + t;
        f4 v = wsrc[cb];
        int lin = cb * 16;
        int c = cb >> 4;
        *(f4*)((char*)Bsw + (lin ^ ((c & 7) << 4))) = v;
    }
}

// ---------- gemm1 body: g1 = fp16(x @ W1), segment-major out; A in regs (hi+lo) ----------
__device__ __forceinline__ void gemm1_body(char* smem, int blk,
                                           const float* __restrict__ src,
                                           const __half* __restrict__ Wt,
                                           __half* __restrict__ g16, int nrows) {
    _Float16* Bsw = (_Float16*)smem;   // 32 KB
    stage_B(Bsw, Wt);

    int t = threadIdx.x;
    int w = t >> 6, lane = t & 63;
    int li = lane & 15, hg = lane >> 4;
    int r = blk * 64 + w * 16 + li;
    int rc = r < nrows ? r : nrows - 1;
    const float* xr = src + (size_t)rc * 128;

    f16x8 af[4], al[4];
#pragma unroll
    for (int kk = 0; kk < 4; ++kk) {
        f4 v0 = *(const f4*)(xr + kk * 32 + hg * 8);
        f4 v1 = *(const f4*)(xr + kk * 32 + hg * 8 + 4);
#pragma unroll
        for (int u = 0; u < 4; ++u) {
            float a0 = v0[u]; _Float16 h0 = (_Float16)a0;
            af[kk][u] = h0;     al[kk][u]     = (_Float16)(a0 - (float)h0);
            float a1 = v1[u]; _Float16 h1 = (_Float16)a1;
            af[kk][u + 4] = h1; al[kk][u + 4] = (_Float16)(a1 - (float)h1);
        }
    }
    __syncthreads();   // B ready (A loads overlapped with B staging)

    f32x4 acc[8];
#pragma unroll
    for (int nn = 0; nn < 8; ++nn) acc[nn] = (f32x4)0.0f;
#pragma unroll
    for (int nn = 0; nn < 8; ++nn) {
        int c = nn * 16 + li;
        int cbase = c * 256;
        int sw = (c & 7) << 4;
#pragma unroll
        for (int kk = 0; kk < 4; ++kk) {
            f16x8 bf = *(const f16x8*)((const char*)Bsw + ((cbase + kk * 64 + hg * 16) ^ sw));
            acc[nn] = __builtin_amdgcn_mfma_f32_16x16x32_f16(af[kk], bf, acc[nn], 0, 0, 0);
            acc[nn] = __builtin_amdgcn_mfma_f32_16x16x32_f16(al[kk], bf, acc[nn], 0, 0, 0);
        }
    }

    // epilogue: C/D col = lane&15, row = (lane>>4)*4 + reg (m89); SEGMENT-MAJOR store
    int gr0 = blk * 64 + w * 16 + (hg << 2);
#pragma unroll
    for (int nn = 0; nn < 8; ++nn) {
        int c = nn * 16 + li;
        int p = c >> 5, cs = c & 31;
        __half* seg = g16 + (size_t)p * nrows * 32;
#pragma unroll
        for (int q = 0; q < 4; ++q) {
            int rr = gr0 + q;
            if (rr < nrows)
                seg[(size_t)rr * 32 + cs] = __float2half(acc[nn][q]);
        }
    }
}

// ---------- bin body: 2048 edges/block -> packed (row<<8 | node_in_bucket) ----------
__device__ __forceinline__ void bin_body(char* smem, int bb,
                                         const int* __restrict__ row,
                                         const int* __restrict__ col,
                                         int* __restrict__ gcur,
                                         uint32_t* __restrict__ binned,
                                         int E, int n, int nbuck) {
    int* hist = (int*)smem;
    int* base = (int*)(smem + 1024);
    int t = threadIdx.x;
    hist[t] = 0;
    __syncthreads();
    int e0 = bb * 2048 + t;
    int cc[8]; uint32_t pk[8];
#pragma unroll
    for (int i = 0; i < 8; ++i) {
        int e = e0 + i * 256;
        cc[i] = -1; pk[i] = 0;
        if (e < E) {
            int c = col[e];
            if ((unsigned)c < (unsigned)n) {
                cc[i] = c >> BSHIFT;
                pk[i] = ((uint32_t)row[e] << BSHIFT) | (uint32_t)(c & BMASK);
            }
        }
    }
#pragma unroll
    for (int i = 0; i < 8; ++i)
        if (cc[i] >= 0) atomicAdd(&hist[cc[i]], 1);
    __syncthreads();
    if (t < nbuck) {
        int h = hist[t];
        if (h) base[t] = atomicAdd(&gcur[t], h);
        hist[t] = 0;
    }
    __syncthreads();
#pragma unroll
    for (int i = 0; i < 8; ++i)
        if (cc[i] >= 0) {
            int b = cc[i];
            int p = base[b] + atomicAdd(&hist[b], 1);
            if (p < BCAP) binned[(size_t)b * BCAP + p] = pk[i];
        }
}

// ---------- fused kernel1: gemm1 blocks + bin blocks (disjoint roles, 32 KB LDS) ----------
__global__ __launch_bounds__(256) void gemm_bin_kernel(const float* __restrict__ src,
                                                       const __half* __restrict__ Wt,
                                                       __half* __restrict__ g16,
                                                       int nrows, int gblocks,
                                                       const int* __restrict__ row,
                                                       const int* __restrict__ col,
                                                       int* __restrict__ gcur,
                                                       uint32_t* __restrict__ binned,
                                                       int E, int n, int nbuck) {
    __shared__ char smem[32768];
    if ((int)blockIdx.x < gblocks)
        gemm1_body(smem, blockIdx.x, src, Wt, g16, nrows);
    else
        bin_body(smem, blockIdx.x - gblocks, row, col, gcur, binned, E, n, nbuck);
}

// ---------- gemm2: g2 = fp16(dinv * (act1 @ W2)); segment-major in AND out ----------
__global__ __launch_bounds__(256) void gemm2_kernel(const __half* __restrict__ act16,
                                                    const __half* __restrict__ Wt,
                                                    const float* __restrict__ dinv,
                                                    __half* __restrict__ g16, int nrows) {
    __shared__ char smem[32768];
    _Float16* Bsw = (_Float16*)smem;
    stage_B(Bsw, Wt);

    int t = threadIdx.x;
    int w = t >> 6, lane = t & 63;
    int li = lane & 15, hg = lane >> 4;
    int r = blockIdx.x * 64 + w * 16 + li;
    int rc = r < nrows ? r : nrows - 1;

    // A-frag: row rc, k = kk*32 + hg*8 .. +7  ->  segment kk, offset hg*8
    f16x8 af[4];
#pragma unroll
    for (int kk = 0; kk < 4; ++kk)
        af[kk] = *(const f16x8*)((const _Float16*)act16 + (size_t)kk * nrows * 32
                                 + (size_t)rc * 32 + hg * 8);
    __syncthreads();

    f32x4 acc[8];
#pragma unroll
    for (int nn = 0; nn < 8; ++nn) acc[nn] = (f32x4)0.0f;
#pragma unroll
    for (int nn = 0; nn < 8; ++nn) {
        int c = nn * 16 + li;
        int cbase = c * 256;
        int sw = (c & 7) << 4;
#pragma unroll
        for (int kk = 0; kk < 4; ++kk) {
            f16x8 bf = *(const f16x8*)((const char*)Bsw + ((cbase + kk * 64 + hg * 16) ^ sw));
            acc[nn] = __builtin_amdgcn_mfma_f32_16x16x32_f16(af[kk], bf, acc[nn], 0, 0, 0);
        }
    }

    int gr0 = blockIdx.x * 64 + w * 16 + (hg << 2);
    float dv[4];
#pragma unroll
    for (int q = 0; q < 4; ++q) {
        int rr = gr0 + q;
        dv[q] = dinv[rr < nrows ? rr : 0];
    }
#pragma unroll
    for (int nn = 0; nn < 8; ++nn) {
        int c = nn * 16 + li;
        int p = c >> 5, cs = c & 31;
        __half* seg = g16 + (size_t)p * nrows * 32;
#pragma unroll
        for (int q = 0; q < 4; ++q) {
            int rr = gr0 + q;
            if (rr < nrows)
                seg[(size_t)rr * 32 + cs] = __float2half(acc[nn][q] * dv[q]);
        }
    }
}

// ---------- bucket: 1024 threads/block, per 256-node bucket -> off / dinv / csr ----------
__global__ __launch_bounds__(1024) void bucket_kernel(const uint32_t* __restrict__ binned,
                                                      const int* __restrict__ gcur,
                                                      int* __restrict__ off,
                                                      float* __restrict__ dinv,
                                                      int* __restrict__ csr,
                                                      int n, int nbuck) {
    __shared__ int wtot[4];
    __shared__ int sbase[256];
    __shared__ int hist[256];
    __shared__ int cur[256];
    int t = threadIdx.x;
    int lane = t & 63, w = t >> 6;
    int b = blockIdx.x;

    int v = 0, inc = 0;
    if (t < 256) {
        v = (t < nbuck) ? gcur[t] : 0;
        inc = v;
#pragma unroll
        for (int d = 1; d < 64; d <<= 1) { int u = __shfl_up(inc, d); if (lane >= d) inc += u; }
        if (lane == 63) wtot[w] = inc;
    }
    __syncthreads();
    if (t < 256) {
        int wb = 0;
        for (int i = 0; i < w; ++i) wb += wtot[i];
        sbase[t] = wb + inc - v;
    }
    __syncthreads();
    int base_b = sbase[b];
    int c_b    = gcur[b];

    if (t < 256) hist[t] = 0;
    __syncthreads();
    const uint32_t* reg = binned + (size_t)b * BCAP;
    for (int j = t; j < c_b; j += 1024)
        atomicAdd(&hist[reg[j] & BMASK], 1);
    __syncthreads();

    int h = 0, inc2 = 0;
    if (t < 256) {
        h = hist[t];
        inc2 = h;
#pragma unroll
        for (int d = 1; d < 64; d <<= 1) { int u = __shfl_up(inc2, d); if (lane >= d) inc2 += u; }
        if (lane == 63) wtot[w] = inc2;
    }
    __syncthreads();
    if (t < 256) {
        int wb2 = 0;
        for (int i = 0; i < w; ++i) wb2 += wtot[i];
        int lo = wb2 + inc2 - h;
        int node = (b << BSHIFT) + t;
        if (node < n) {
            off[node]  = base_b + lo;
            dinv[node] = rsqrtf((float)(h + 1));   // +1: self-loop
        }
        cur[t] = base_b + lo;
    }
    if (b == nbuck - 1 && t == 0)
        off[n] = sbase[nbuck - 1] + gcur[nbuck - 1];
    __syncthreads();
    for (int j = t; j < c_b; j += 1024) {
        uint32_t pv = reg[j];
        int p = atomicAdd(&cur[pv & BMASK], 1);
        csr[p] = (int)(pv >> BSHIFT);
    }
}

// ---------- aggregation, column-pass version ----------
// blockIdx.y = pass p (0..3): gathers only sub-table p (3.2 MB -> L2-resident/XCD).
// 16-lane group per node; within a group, edge quad = 4 consecutive lanes
// (egrp = li>>2 selects edge, q = li&3 selects 16-B piece of the 64-B segment);
// 4 edges x 4 gathers/lane in flight per 16-edge chunk. Final reduce: shfl_xor 4,8.
// PRE=0: weight = dinv[idx]; out = relu(di*(di*h_self + Σ w_e*h_e) + b)
// PRE=1: weight = 1;          out = relu(di*(g'_self + Σ g'_e) + b)
template<int OUT16, int PRE>
__global__ __launch_bounds__(256) void agg_pass(const __half* __restrict__ gh,  // seg-major
                                                const int* __restrict__ csr,
                                                const int* __restrict__ off,
                                                const float* __restrict__ dinv,
                                                const f4* __restrict__ bias4,   // [32]
                                                void* __restrict__ outp,
                                                int n) {
    int pass = blockIdx.y;
    int tid  = threadIdx.x;
    int lane = tid & 63;
    int li   = lane & 15;
    int q    = li & 3;          // 16-B piece of the 64-B segment
    int egrp = li >> 2;         // edge sub-slot 0..3
    int gbase = lane & 48;      // group's lane base for shfl

    int node = blockIdx.x * 16 + ((tid >> 6) << 2) + (lane >> 4);
    bool valid = node < n;
    int nodeC = valid ? node : 0;
    float di = dinv[nodeC];

    const _Float16* sub = (const _Float16*)gh + (size_t)pass * n * 32;

    float a[8];
    {
        f16x8 sv = *(const f16x8*)(sub + (size_t)nodeC * 32 + q * 8);  // self piece
        float sc = PRE ? 1.0f : di;
        if (egrp == 0) {
#pragma unroll
            for (int i = 0; i < 8; ++i) a[i] = sc * (float)sv[i];
        } else {
#pragma unroll
            for (int i = 0; i < 8; ++i) a[i] = 0.0f;
        }
    }

    int s = off[nodeC];
    int deg = valid ? (off[nodeC + 1] - s) : 0;

    for (int base = 0; __any(base < deg); base += 16) {
        int idx = 0; float wv = 0.0f;
        if (base + li < deg) {
            idx = csr[s + base + li];             // group-coalesced (16 entries)
            wv  = PRE ? 1.0f : dinv[idx];
        }
        int rem = deg - base;                      // group-uniform
        int rr[4]; float wl[4];
#pragma unroll
        for (int k = 0; k < 4; ++k) {
            int el = egrp + k * 4;                 // edge within chunk
            rr[k] = __shfl(idx, gbase + el);
            wl[k] = PRE ? ((el < rem) ? 1.0f : 0.0f) : __shfl(wv, gbase + el);
        }
        f16x8 v[4];
#pragma unroll
        for (int k = 0; k < 4; ++k)                // 4 x 16B gathers in flight
            v[k] = *(const f16x8*)(sub + (size_t)rr[k] * 32 + q * 8);
#pragma unroll
        for (int k = 0; k < 4; ++k)
#pragma unroll
            for (int i = 0; i < 8; ++i)
                a[i] = fmaf(wl[k], (float)v[k][i], a[i]);
    }

    // reduce the 4 edge sub-slots holding the same piece q (lanes li, li^4, li^8)
#pragma unroll
    for (int i = 0; i < 8; ++i) {
        a[i] += __shfl_xor(a[i], 4);
        a[i] += __shfl_xor(a[i], 8);
    }

    if (valid && egrp == 0) {                      // lanes li<4 write piece q
        int c0 = pass * 32 + q * 8;                // first output col
        f4 bb0 = bias4[c0 >> 2], bb1 = bias4[(c0 >> 2) + 1];
        float o[8];
#pragma unroll
        for (int u = 0; u < 4; ++u) {
            o[u]     = fmaxf(fmaf(di, a[u],     bb0[u]), 0.0f);
            o[4 + u] = fmaxf(fmaf(di, a[4 + u], bb1[u]), 0.0f);
        }
        if (OUT16) {
            f16x8 hv;
#pragma unroll
            for (int u = 0; u < 8; ++u) hv[u] = (_Float16)o[u];
            *(f16x8*)((_Float16*)outp + (size_t)pass * n * 32 + (size_t)node * 32 + q * 8) = hv;
        } else {
            float* op = (float*)outp + (size_t)node * 128 + c0;
            f4 o0, o1;
#pragma unroll
            for (int u = 0; u < 4; ++u) { o0[u] = o[u]; o1[u] = o[4 + u]; }
            *(f4*)op = o0;
            *(f4*)(op + 4) = o1;
        }
    }
}

// ---------- launch ----------
extern "C" void kernel_launch(void* const* d_in, const int* in_sizes, int n_in,
                              void* d_out, int out_size, void* d_ws, size_t ws_size,
                              hipStream_t stream) {
    float*       xbuf = (float*)d_in[0];        // fp32 input; later reused for seg-major g2
    const int*   ei   = (const int*)d_in[1];
    const float* W1   = (const float*)d_in[2];
    const float* b1   = (const float*)d_in[3];
    const float* W2   = (const float*)d_in[4];
    const float* b2   = (const float*)d_in[5];
    float*       out  = (float*)d_out;

    int N = in_sizes[0] / 128;
    int E = in_sizes[1] / 2;
    const int* row = ei;          // sources (x_j)
    const int* col = ei + E;      // targets (aggregate index)

    int nbuck = (N + 255) >> BSHIFT;   // 196 for N=50000

    auto align256 = [](size_t v) { return (v + 255) & ~(size_t)255; };
    char* ws = (char*)d_ws;
    size_t pos = 0;
    int*      off    = (int*)(ws + pos);      pos += align256((size_t)(N + 1) * 4);
    float*    dinv   = (float*)(ws + pos);    pos += align256((size_t)N * 4);
    int*      csr    = (int*)(ws + pos);      pos += align256((size_t)E * 4);
    int*      gcur   = (int*)(ws + pos);      pos += align256(256 * 4);
    uint32_t* binned = (uint32_t*)(ws + pos); pos += align256((size_t)nbuck * BCAP * 4);
    __half*   Wt1    = (__half*)(ws + pos);   pos += align256(128 * 128 * 2);
    __half*   Wt2    = (__half*)(ws + pos);   pos += align256(128 * 128 * 2);
    // total ~10 MB

    // buffer routing (all SEGMENT-MAJOR fp16 tables, nothing in-place):
    //   g1c   : d_out upper half (written by gemm1, read by agg1)
    //   act16 : d_out lower half (written by agg1, read by gemm2)
    //   g2c   : xbuf             (written by gemm2 after xbuf consumed by gemm1)
    //   final : d_out full       (written by agg2; g1c/act16 dead by then)
    __half* act16 = (__half*)out;
    __half* g1c   = (__half*)((char*)out + (size_t)N * 256);
    __half* g2c   = (__half*)xbuf;

    int binblocks = (E + 2047) / 2048;
    int gblocks   = (N + 63) / 64;
    int ablocks   = (N + 15) / 16;     // 16 nodes per block
    dim3 agrid(ablocks, 4);            // y = column pass (dispatch order: pass 0 first)

    // prep: zero gcur + transpose both W's (replaces memset)
    prep_kernel<<<17, 256, 0, stream>>>(W1, W2, Wt1, Wt2, gcur);
    // fused: gemm1 (graph-independent — dinv deferred to agg) + bin
    gemm_bin_kernel<<<gblocks + binblocks, 256, 0, stream>>>(xbuf, Wt1, g1c, N, gblocks,
                                                             row, col, gcur, binned,
                                                             E, N, nbuck);
    bucket_kernel<<<nbuck, 1024, 0, stream>>>(binned, gcur, off, dinv, csr, N, nbuck);

    // layer 1: act1 = relu(di*(di*h_self + Σ dv*h) + b1) -> seg-major fp16 (d_out lower)
    agg_pass<1, 0><<<agrid, 256, 0, stream>>>(g1c, csr, off, dinv, (const f4*)b1, act16, N);
    // layer 2: g2' = fp16(dinv * (act1 @ W2)) -> xbuf (seg-major, pre-scaled rows)
    gemm2_kernel<<<gblocks, 256, 0, stream>>>(act16, Wt2, dinv, g2c, N);
    // agg2: out = relu(di*(g'_self + Σ g'_e) + b2) — row-major f32 final output
    agg_pass<0, 1><<<agrid, 256, 0, stream>>>(g2c, csr, off, dinv, (const f4*)b2, out, N);
}